// Round 6
// baseline (158.107 us; speedup 1.0000x reference)
//
#include <hip/hip_runtime.h>
#include <math.h>

#define BB 32
#define NN 96
#define DD 32
#define FF 16
#define NE (NN * NN)          // 9216 edges per batch
#define PAIRS (BB * NN)       // 3072 (b,i) pairs
#define PPB 6                 // pairs per block; 2 pairs processed concurrently
#define GRID_F (PAIRS / PPB)  // 512 blocks = 2/CU
#define EG 6                  // edges per inner group

// ---------------------------------------------------------------------------
// Fused kernel: per (b,i):  A=relu(edges@W+b); m = sum_j mask*A·nodes[j];
// then the 2-step GRU for the block's 6 rows (reusing LDS for GRU weights).
//
// Lane->k map (b128-friendly, single-register aggregate):
//   8 waves: psel = wv>>2 picks one of 2 concurrent pairs, tq = wv&3 picks the
//   k-chunk [256tq, 256tq+256). Lane l owns k = 256tq + 4l + c, c=0..3:
//     p = k>>5 = 8tq + (l>>3)  (constant per lane -> aggacc is ONE register)
//     q = k&31 = 4(l&7) + c    (float4 of nodes[j], 8-way broadcast read)
//   W read per f: ds_read_b128 at Wl[f*1024 + wbase] - contiguous, conflict-free.
//   Each wave owns p-range [8tq,8tq+8) exclusively -> no atomics on output.
//
// Round-5 change: rolling 1-chunk prefetch. Round 4 loaded each 16B edge
// chunk right before its FMAs -> first chunk of every group was an
// HBM/L2 miss (~200-900cy) with no cover -> VALUBusy 49%, 92us. Now chunk
// u+1 (or next group's u0) is issued before chunk u's FMAs; next group's
// jj ds_reads issue at group top so their latency hides under u0-u2 FMAs.
// Per-edge arithmetic order unchanged (bias-first, u/f2 ascending).
// __launch_bounds__(512,2): empirical VGPR cap 128 (r1: arg2=2->128,
// r2: arg2=4->64). Live set ~115 -> fits, 2 blocks/CU, 4 waves/SIMD.
// Mask==0 edges skipped exactly (mask is exactly 0.0/1.0).
// ---------------------------------------------------------------------------
__device__ __forceinline__ float dot32(const float* __restrict__ x,
                                       const float* __restrict__ w) {
    float s = 0.f;
    #pragma unroll
    for (int u = 0; u < 8; ++u) {
        float4 a = *(const float4*)(x + 4 * u);
        float4 c = *(const float4*)(w + 4 * u);
        s = fmaf(a.x, c.x, fmaf(a.y, c.y, fmaf(a.z, c.z, fmaf(a.w, c.w, s))));
    }
    return s;
}
__device__ __forceinline__ float sigm(float x) { return 1.f / (1.f + expf(-x)); }

__global__ __launch_bounds__(512, 2)
void mp_fused(const float* __restrict__ nodes, const float* __restrict__ edges,
              const float* __restrict__ mask, const float* __restrict__ W_agg,
              const float* __restrict__ b_agg,
              const float* __restrict__ w_ih, const float* __restrict__ w_hh,
              const float* __restrict__ b_ih, const float* __restrict__ b_hh,
              float* __restrict__ out) {
    __shared__ __align__(16) float Wl[FF * 1024];   // 64 KB; reused for GRU wts
    __shared__ __align__(16) float nodl[NN * DD];   // 12 KB
    __shared__ int jlist[2][NN];
    __shared__ int jcnt[2];
    __shared__ __align__(16) float aggv[PPB][DD];
    __shared__ __align__(16) float h1v[PPB][DD];
    __shared__ float bih_s[96], bhh_s[96];

    const int tid  = threadIdx.x;
    const int lane = tid & 63;
    const int wv   = tid >> 6;       // 0..7
    const int tq   = wv & 3;         // k-chunk
    const int psel = wv >> 2;        // which of 2 concurrent pairs
    const int pair0 = blockIdx.x * PPB;
    const int b  = pair0 / NN;
    const int i0 = pair0 % NN;
    const int l8 = lane & 7;         // q-chunk id
    const int lp = lane >> 3;        // p offset within chunk
    const int wbase = 256 * tq + 4 * lane;

    // stage W_agg (4096 float4) and nodes[b] (768 float4)
    for (int v = tid; v < 4096; v += 512)
        ((float4*)Wl)[v] = ((const float4*)W_agg)[v];
    for (int v = tid; v < 768; v += 512)
        ((float4*)nodl)[v] = ((const float4*)(nodes + b * NN * DD))[v];

    const float4 bvv = *(const float4*)(b_agg + wbase);

    for (int pr = 0; pr < 3; ++pr) {
        __syncthreads();             // prev round's jlist reads done (+staging)
        if (tid < 2) jcnt[tid] = 0;
        __syncthreads();
        // compact unmasked edges for the 2 pairs (order irrelevant to sum)
        if (tid < 2 * NN) {
            const int ps = tid / NN, col = tid % NN;
            const int ii = i0 + 2 * pr + ps;
            if (mask[(size_t)b * NE + (size_t)ii * NN + col] != 0.f) {
                int p = atomicAdd(&jcnt[ps], 1);
                jlist[ps][p] = col;
            }
        }
        __syncthreads();
        const int i = i0 + 2 * pr + psel;
        const int cnt = __builtin_amdgcn_readfirstlane(jcnt[psel]);
        const float4* ebase4 =
            (const float4*)(edges + ((size_t)b * NE + (size_t)i * NN) * FF);

        float aggacc = 0.f;
        if (cnt > 0) {
            // prologue: group-0 indices + their u0 chunks
            int jjc[EG];
            #pragma unroll
            for (int e = 0; e < EG; ++e) {
                int idx = e; if (idx > cnt - 1) idx = cnt - 1;
                jjc[e] = __builtin_amdgcn_readfirstlane(jlist[psel][idx]);
            }
            float4 cur[EG];
            #pragma unroll
            for (int e = 0; e < EG; ++e) cur[e] = ebase4[jjc[e] * 4];

            for (int e0 = 0; e0 < cnt; e0 += EG) {
                const bool haveNext = (e0 + EG < cnt);
                // next group's indices: ds_read latency hides under u0-u2 FMAs
                int jjn[EG];
                #pragma unroll
                for (int e = 0; e < EG; ++e) {
                    int idx = e0 + EG + e; if (idx > cnt - 1) idx = cnt - 1;
                    jjn[e] = __builtin_amdgcn_readfirstlane(jlist[psel][idx]);
                }
                float acc[EG][4];
                #pragma unroll
                for (int e = 0; e < EG; ++e) {
                    acc[e][0] = bvv.x; acc[e][1] = bvv.y;
                    acc[e][2] = bvv.z; acc[e][3] = bvv.w;
                }
                float4 nxt[EG];
                #pragma unroll
                for (int u = 0; u < 4; ++u) {
                    // prefetch one chunk ahead of use
                    if (u < 3) {
                        #pragma unroll
                        for (int e = 0; e < EG; ++e)
                            nxt[e] = ebase4[jjc[e] * 4 + (u + 1)];
                    } else if (haveNext) {
                        #pragma unroll
                        for (int e = 0; e < EG; ++e)
                            nxt[e] = ebase4[jjn[e] * 4];
                    }
                    #pragma unroll
                    for (int f2 = 0; f2 < 4; ++f2) {
                        const float4 w4 =
                            *(const float4*)(Wl + (4 * u + f2) * 1024 + wbase);
                        #pragma unroll
                        for (int e = 0; e < EG; ++e) {
                            const float ef = (f2 == 0) ? cur[e].x
                                           : (f2 == 1) ? cur[e].y
                                           : (f2 == 2) ? cur[e].z : cur[e].w;
                            acc[e][0] = fmaf(ef, w4.x, acc[e][0]);
                            acc[e][1] = fmaf(ef, w4.y, acc[e][1]);
                            acc[e][2] = fmaf(ef, w4.z, acc[e][2]);
                            acc[e][3] = fmaf(ef, w4.w, acc[e][3]);
                        }
                    }
                    if (u < 3) {
                        #pragma unroll
                        for (int e = 0; e < EG; ++e) cur[e] = nxt[e];
                    }
                }
                // epilogue: relu * nodes[j][q-chunk], lane-private accumulate
                #pragma unroll
                for (int e = 0; e < EG; ++e) {
                    if (e0 + e < cnt) {
                        const float4 x4 =
                            *(const float4*)(nodl + jjc[e] * DD + 4 * l8);
                        aggacc = fmaf(fmaxf(acc[e][0], 0.f), x4.x, aggacc);
                        aggacc = fmaf(fmaxf(acc[e][1], 0.f), x4.y, aggacc);
                        aggacc = fmaf(fmaxf(acc[e][2], 0.f), x4.z, aggacc);
                        aggacc = fmaf(fmaxf(acc[e][3], 0.f), x4.w, aggacc);
                    }
                }
                // rotate to next group
                #pragma unroll
                for (int e = 0; e < EG; ++e) jjc[e] = jjn[e];
                if (haveNext) {
                    #pragma unroll
                    for (int e = 0; e < EG; ++e) cur[e] = nxt[e];
                }
            }
        }
        // reduce the 8 q-chunks (lanes sharing lane>>3)
        aggacc += __shfl_xor(aggacc, 1, 64);
        aggacc += __shfl_xor(aggacc, 2, 64);
        aggacc += __shfl_xor(aggacc, 4, 64);
        if (l8 == 0) aggv[2 * pr + psel][8 * tq + lp] = aggacc;
    }

    // ---- GRU phase: reuse Wl region for w_ih/w_hh (padded stride 36) ----
    __syncthreads();
    float* wihL = Wl;                // 96*36 = 3456 floats
    float* whhL = Wl + 3456;
    for (int v = tid; v < 768; v += 512) {
        int row = v >> 3, c4 = v & 7;
        *(float4*)&wihL[row * 36 + c4 * 4] = ((const float4*)w_ih)[v];
        *(float4*)&whhL[row * 36 + c4 * 4] = ((const float4*)w_hh)[v];
    }
    if (tid < 96) { bih_s[tid] = b_ih[tid]; bhh_s[tid] = b_hh[tid]; }
    __syncthreads();

    if (tid < PPB * DD) {
        const int pp = tid >> 5, d = tid & 31;
        const float* x = nodl + (i0 + pp) * DD;
        // cell 1: h = 0 -> gh = b_hh exactly
        float gi_r = dot32(x, &wihL[(0 * 32 + d) * 36]) + bih_s[d];
        float gi_z = dot32(x, &wihL[(1 * 32 + d) * 36]) + bih_s[32 + d];
        float gi_n = dot32(x, &wihL[(2 * 32 + d) * 36]) + bih_s[64 + d];
        float r1 = sigm(gi_r + bhh_s[d]);
        float z1 = sigm(gi_z + bhh_s[32 + d]);
        float n1 = tanhf(gi_n + r1 * bhh_s[64 + d]);
        h1v[pp][d] = (1.f - z1) * n1;
    }
    __syncthreads();
    if (tid < PPB * DD) {
        const int pp = tid >> 5, d = tid & 31;
        const float* a  = &aggv[pp][0];
        const float* h1 = &h1v[pp][0];
        float gi_r = dot32(a, &wihL[(0 * 32 + d) * 36]) + bih_s[d];
        float gi_z = dot32(a, &wihL[(1 * 32 + d) * 36]) + bih_s[32 + d];
        float gi_n = dot32(a, &wihL[(2 * 32 + d) * 36]) + bih_s[64 + d];
        float gh_r = dot32(h1, &whhL[(0 * 32 + d) * 36]) + bhh_s[d];
        float gh_z = dot32(h1, &whhL[(1 * 32 + d) * 36]) + bhh_s[32 + d];
        float gh_n = dot32(h1, &whhL[(2 * 32 + d) * 36]) + bhh_s[64 + d];
        float r2 = sigm(gi_r + gh_r);
        float z2 = sigm(gi_z + gh_z);
        float n2 = tanhf(gi_n + r2 * gh_n);
        float h2 = (1.f - z2) * n2 + z2 * h1[d];
        out[(size_t)(pair0 + pp) * DD + d] = h2;
    }
}

extern "C" void kernel_launch(void* const* d_in, const int* in_sizes, int n_in,
                              void* d_out, int out_size, void* d_ws, size_t ws_size,
                              hipStream_t stream) {
    const float* nodes = (const float*)d_in[0];
    const float* edges = (const float*)d_in[1];
    const float* mask  = (const float*)d_in[2];
    const float* W_agg = (const float*)d_in[3];
    const float* b_agg = (const float*)d_in[4];
    const float* w_ih  = (const float*)d_in[5];
    const float* w_hh  = (const float*)d_in[6];
    const float* b_ih  = (const float*)d_in[7];
    const float* b_hh  = (const float*)d_in[8];
    float* out = (float*)d_out;

    mp_fused<<<GRID_F, 512, 0, stream>>>(nodes, edges, mask, W_agg, b_agg,
                                         w_ih, w_hh, b_ih, b_hh, out);
}